// Round 4
// baseline (71.626 us; speedup 1.0000x reference)
//
#include <hip/hip_runtime.h>

#define T_DIM 1024

typedef short short8 __attribute__((ext_vector_type(8)));
typedef float f32x4  __attribute__((ext_vector_type(4)));

__device__ __forceinline__ unsigned pk_bf16(float lo, float hi) {
    unsigned r;
    asm("v_cvt_pk_bf16_f32 %0, %1, %2" : "=v"(r) : "v"(lo), "v"(hi));
    return r;   // [15:0]=bf16(lo), [31:16]=bf16(hi)
}

// Pack K (3,8,256) f32 -> bf16 B-fragments: Kp[kb*256+col] = short8 of
// K[(kb*8+e)*256+col], e=0..7; kb==3 is the K-dim zero padding (24->32).
__global__ void kpack_kernel(const float* __restrict__ K, uint4* __restrict__ Kp) {
    const int col = threadIdx.x;
    #pragma unroll
    for (int kb = 0; kb < 4; ++kb) {
        uint4 wv = make_uint4(0u, 0u, 0u, 0u);
        if (kb < 3) {
            const float* kp = K + kb * 8 * 256 + col;
            wv.x = pk_bf16(kp[0 * 256], kp[1 * 256]);
            wv.y = pk_bf16(kp[2 * 256], kp[3 * 256]);
            wv.z = pk_bf16(kp[4 * 256], kp[5 * 256]);
            wv.w = pk_bf16(kp[6 * 256], kp[7 * 256]);
        }
        Kp[kb * 256 + col] = wv;
    }
}

// One block per (b,t), 4 independent waves, ZERO LDS, zero barriers.
// Conv: U[32x256] = X[32x32]*K[32x256] via 8 MFMA/wave (A from global x with
//   in-reg cvt_pk; B from pre-packed Kp). MFMA tile (w,i) = exactly head
//   h=w*4+i: lane(kb,r16) holds U[q = mi*16+kb*4+e][d = r16].
// Attention per head entirely in-wave: V (shfl 16/32), scores (butterfly
//   allreduce masks 1/2/4/8 over d), softmax (in-thread 8 q + shfl 16/32),
//   out (shfl 16/32), norm gate (masks 1..8), 16-lane store.
__global__ __launch_bounds__(256, 4) void caps_kernel(
    const float* __restrict__ x,     // (B,T,32,8)
    const float* __restrict__ bias,  // (256)
    const float* __restrict__ Bw,    // (T,16,1,32)
    const uint4* __restrict__ Kp,    // packed bf16 K fragments
    float* __restrict__ out)         // (B,T,16,16)
{
    const int bt  = blockIdx.x;
    const int t   = bt & (T_DIM - 1);
    const int l   = threadIdx.x & 63;
    const int w   = threadIdx.x >> 6;
    const int kb  = l >> 4;
    const int r16 = l & 15;

    // ---- A fragments: x rows t-1..t+1 (kt == kb), SAME-pad via zero ----
    const int  tt    = t + kb - 1;
    const bool valid = (kb < 3) && (tt >= 0) && (tt < T_DIM);
    short8 a[2];
    #pragma unroll
    for (int mi = 0; mi < 2; ++mi) {
        float4 x0 = make_float4(0.f, 0.f, 0.f, 0.f), x1 = x0;
        if (valid) {
            const float* xp = x + ((size_t)(bt + kb - 1) * 256 + (mi * 16 + r16) * 8);
            x0 = *reinterpret_cast<const float4*>(xp);
            x1 = *reinterpret_cast<const float4*>(xp + 4);
        }
        union { short8 s; uint4 u; } au;
        au.u.x = pk_bf16(x0.x, x0.y);
        au.u.y = pk_bf16(x0.z, x0.w);
        au.u.z = pk_bf16(x1.x, x1.y);
        au.u.w = pk_bf16(x1.z, x1.w);
        a[mi] = au.s;
    }

    // ---- B fragments (coalesced b128, L1-hot) + bias + Bw prefetch ----
    short8 bfrag[4];
    float  bo[4];
    float4 bw0[4], bw1[4];
    const float* bwB = Bw + (size_t)t * 512;
    #pragma unroll
    for (int i = 0; i < 4; ++i) {
        const int col  = w * 64 + i * 16 + r16;
        const int head = w * 4 + i;
        union { short8 s; uint4 u; } bu;
        bu.u = Kp[kb * 256 + col];
        bfrag[i] = bu.s;
        bo[i]  = bias[col];
        bw0[i] = *reinterpret_cast<const float4*>(bwB + head * 32 + kb * 4);
        bw1[i] = *reinterpret_cast<const float4*>(bwB + head * 32 + 16 + kb * 4);
    }

    // ---- conv MFMAs ----
    f32x4 acc[2][4];
    #pragma unroll
    for (int mi = 0; mi < 2; ++mi)
        #pragma unroll
        for (int i = 0; i < 4; ++i) {
            acc[mi][i] = (f32x4){0.f, 0.f, 0.f, 0.f};
            acc[mi][i] = __builtin_amdgcn_mfma_f32_16x16x32_bf16(
                a[mi], bfrag[i], acc[mi][i], 0, 0, 0);
        }

    // ---- per-head epilogue, all cross-lane ----
    const float is8 = 0.35355339059327373f;   // 1/sqrt(8)
    #pragma unroll
    for (int i = 0; i < 4; ++i) {
        const int head = w * 4 + i;

        // U values this lane owns: q = mi*16 + kb*4 + e, d = r16
        float Uv[8];
        #pragma unroll
        for (int mi = 0; mi < 2; ++mi)
            #pragma unroll
            for (int e = 0; e < 4; ++e)
                Uv[mi * 4 + e] = fmaxf(acc[mi][i][e] + bo[i], 0.f);

        // V[d] = sum_q U[q][d] (own 8 + kb lanes), pre-scaled by 1/sqrt(8)
        float vs = ((Uv[0] + Uv[1]) + (Uv[2] + Uv[3])) +
                   ((Uv[4] + Uv[5]) + (Uv[6] + Uv[7]));
        vs += __shfl_xor(vs, 16);
        vs += __shfl_xor(vs, 32);
        vs *= is8;

        // s[q] = sum_d V[d]*U[q][d]: butterfly allreduce over d (r16 bits)
        float p[8];
        #pragma unroll
        for (int z = 0; z < 8; ++z) p[z] = vs * Uv[z];
        #pragma unroll
        for (int mask = 1; mask <= 8; mask <<= 1) {
            #pragma unroll
            for (int z = 0; z < 8; ++z) p[z] += __shfl_xor(p[z], mask);
        }

        // softmax over 32 q (8 in-thread + kb lanes)
        float m = fmaxf(fmaxf(fmaxf(p[0], p[1]), fmaxf(p[2], p[3])),
                        fmaxf(fmaxf(p[4], p[5]), fmaxf(p[6], p[7])));
        m = fmaxf(m, __shfl_xor(m, 16));
        m = fmaxf(m, __shfl_xor(m, 32));
        float ex[8], es = 0.f;
        #pragma unroll
        for (int z = 0; z < 8; ++z) { ex[z] = __expf(p[z] - m); es += ex[z]; }
        es += __shfl_xor(es, 16);
        es += __shfl_xor(es, 32);
        const float inv = __builtin_amdgcn_rcpf(es);

        // c[q] = softmax + Bw;  out[d] = sum_q c[q]*U[q][d]
        float po;
        {
            const float4 b0 = bw0[i], b1 = bw1[i];
            po  = fmaf(ex[0], inv, b0.x) * Uv[0];
            po += fmaf(ex[1], inv, b0.y) * Uv[1];
            po += fmaf(ex[2], inv, b0.z) * Uv[2];
            po += fmaf(ex[3], inv, b0.w) * Uv[3];
            po += fmaf(ex[4], inv, b1.x) * Uv[4];
            po += fmaf(ex[5], inv, b1.y) * Uv[5];
            po += fmaf(ex[6], inv, b1.z) * Uv[6];
            po += fmaf(ex[7], inv, b1.w) * Uv[7];
        }
        po += __shfl_xor(po, 16);
        po += __shfl_xor(po, 32);

        // norm gate over d
        float ss = po * po;
        #pragma unroll
        for (int mask = 1; mask <= 8; mask <<= 1) ss += __shfl_xor(ss, mask);
        const float nrm = sqrtf(ss);
        const float res = ss * __builtin_amdgcn_rcpf(ss + 1.f) *
                          (po * __builtin_amdgcn_rcpf(nrm + 1e-7f));

        if (l < 16)
            out[(size_t)bt * 256 + head * 16 + r16] = res;
    }
}

extern "C" void kernel_launch(void* const* d_in, const int* in_sizes, int n_in,
                              void* d_out, int out_size, void* d_ws, size_t ws_size,
                              hipStream_t stream) {
    const float* x    = (const float*)d_in[0];
    const float* K    = (const float*)d_in[1];
    const float* bias = (const float*)d_in[2];
    const float* Bw   = (const float*)d_in[3];
    float* out        = (float*)d_out;
    uint4* Kp         = (uint4*)d_ws;            // 4*256*16B = 16 KB scratch

    kpack_kernel<<<1, 256, 0, stream>>>(K, Kp);

    const int B  = in_sizes[0] / (T_DIM * 32 * 8);   // = 8
    const int nb = B * T_DIM;                        // 8192 blocks
    caps_kernel<<<nb, 256, 0, stream>>>(x, bias, Bw, Kp, out);
}

// Round 5
// 40.279 us; speedup vs baseline: 1.7782x; 1.7782x over previous
//
#include <hip/hip_runtime.h>

#define T_DIM 1024

typedef short short8 __attribute__((ext_vector_type(8)));
typedef float f32x4  __attribute__((ext_vector_type(4)));

__device__ __forceinline__ unsigned pk_bf16(float lo, float hi) {
    unsigned r;
    asm("v_cvt_pk_bf16_f32 %0, %1, %2" : "=v"(r) : "v"(lo), "v"(hi));
    return r;   // [15:0]=bf16(lo), [31:16]=bf16(hi)
}

// Pack K (3,8,256) f32 -> bf16 B-fragments once per launch.
__global__ void kpack_kernel(const float* __restrict__ K, uint4* __restrict__ Kp) {
    const int col = threadIdx.x;
    #pragma unroll
    for (int kb = 0; kb < 4; ++kb) {
        uint4 wv = make_uint4(0u, 0u, 0u, 0u);
        if (kb < 3) {
            const float* kp = K + kb * 8 * 256 + col;
            wv.x = pk_bf16(kp[0 * 256], kp[1 * 256]);
            wv.y = pk_bf16(kp[2 * 256], kp[3 * 256]);
            wv.z = pk_bf16(kp[4 * 256], kp[5 * 256]);
            wv.w = pk_bf16(kp[6 * 256], kp[7 * 256]);
        }
        Kp[kb * 256 + col] = wv;
    }
}

// Wave-local DS fence: all LDS sharing in this kernel is intra-wave, so a
// lgkmcnt(0) wait replaces __syncthreads(). memory clobber orders DS ops;
// sched_barrier pins the MI scheduler (rule #18).
__device__ __forceinline__ void wave_ds_fence() {
    __builtin_amdgcn_sched_barrier(0);
    asm volatile("s_waitcnt lgkmcnt(0)" ::: "memory");
    __builtin_amdgcn_sched_barrier(0);
}

// One block per (b,t), 4 waves, ZERO barriers.
// Phase 1: conv U[32x256] = X[32x32]*K[32x256], 8 MFMA/wave; A-frags straight
//   from global x (cvt_pk), B-frags from pre-packed Kp. Epilogue: bias+relu,
//   per-head V via 2 shuffles, write Ut[col][slot] (stride 36, rot=8*(n&3):
//   all access classes verified <=2-way banks) + Vs[tid].
// Phase 2 (thread = o = tid): scores via 32 b32 reads (2-way), softmax via
//   16-lane shuffles, cs broadcast through LDS, out + norm gate from regs.
__global__ __launch_bounds__(256, 4) void caps_kernel(
    const float* __restrict__ x,     // (B,T,32,8)
    const float* __restrict__ bias,  // (256)
    const float* __restrict__ Bw,    // (T,16,1,32)
    const uint4* __restrict__ Kp,    // packed bf16 K fragments
    float* __restrict__ out)         // (B,T,16,16)
{
    const int bt  = blockIdx.x;
    const int t   = bt & (T_DIM - 1);
    const int tid = threadIdx.x;
    const int l   = tid & 63;
    const int w   = tid >> 6;
    const int kb  = l >> 4;
    const int r16 = l & 15;

    __shared__ float Ut[256 * 36];   // Ut[col][slot], slot=(q+8*(n&3))&31
    __shared__ float Vs[256];        // V[head][d] pre-scaled by 1/sqrt(8)
    __shared__ float cs[16 * 36];    // c[head][slot]

    // ---- phase-2 operands for THIS thread (issue loads early) ----
    const int n = tid >> 4, j = tid & 15;
    const float bwj0 = Bw[(size_t)t * 512 + n * 32 + j];
    const float bwj1 = Bw[(size_t)t * 512 + n * 32 + 16 + j];

    // ---- A fragments from global x (kt == kb), SAME-pad via zeros ----
    const int  tt    = t + kb - 1;
    const bool valid = (kb < 3) && (tt >= 0) && (tt < T_DIM);
    short8 a[2];
    #pragma unroll
    for (int mi = 0; mi < 2; ++mi) {
        float4 x0 = make_float4(0.f, 0.f, 0.f, 0.f), x1 = x0;
        if (valid) {
            const float* xp = x + ((size_t)(bt + kb - 1) * 256 + (mi * 16 + r16) * 8);
            x0 = *reinterpret_cast<const float4*>(xp);
            x1 = *reinterpret_cast<const float4*>(xp + 4);
        }
        union { short8 s; uint4 u; } au;
        au.u.x = pk_bf16(x0.x, x0.y);
        au.u.y = pk_bf16(x0.z, x0.w);
        au.u.z = pk_bf16(x1.x, x1.y);
        au.u.w = pk_bf16(x1.z, x1.w);
        a[mi] = au.s;
    }

    // ---- B fragments + bias ----
    short8 bfrag[4];
    float  bo[4];
    #pragma unroll
    for (int i = 0; i < 4; ++i) {
        const int col = w * 64 + i * 16 + r16;
        union { short8 s; uint4 u; } bu;
        bu.u = Kp[kb * 256 + col];
        bfrag[i] = bu.s;
        bo[i] = bias[col];
    }

    // ---- conv MFMAs ----
    f32x4 acc[2][4];
    #pragma unroll
    for (int mi = 0; mi < 2; ++mi)
        #pragma unroll
        for (int i = 0; i < 4; ++i) {
            acc[mi][i] = (f32x4){0.f, 0.f, 0.f, 0.f};
            acc[mi][i] = __builtin_amdgcn_mfma_f32_16x16x32_bf16(
                a[mi], bfrag[i], acc[mi][i], 0, 0, 0);
        }

    // ---- epilogue: relu + V + Ut/Vs stores ----
    const float is8 = 0.35355339059327373f;   // 1/sqrt(8)
    float vkeep = 0.f;
    #pragma unroll
    for (int i = 0; i < 4; ++i) {
        const int col = w * 64 + i * 16 + r16;
        float Uv[8];
        #pragma unroll
        for (int mi = 0; mi < 2; ++mi)
            #pragma unroll
            for (int e = 0; e < 4; ++e)
                Uv[mi * 4 + e] = fmaxf(acc[mi][i][e] + bo[i], 0.f);

        // V[d=r16] for head w*4+i: own 8 q's + allreduce over kb lanes
        float vs = ((Uv[0] + Uv[1]) + (Uv[2] + Uv[3])) +
                   ((Uv[4] + Uv[5]) + (Uv[6] + Uv[7]));
        vs += __shfl_xor(vs, 16);
        vs += __shfl_xor(vs, 32);
        if (i == kb) vkeep = vs * is8;   // lane (kb,r16) keeps head kb's V

        const int rot = 8 * (i & 3);     // (col>>4)&3 == i
        #pragma unroll
        for (int mi = 0; mi < 2; ++mi) {
            const int slot = (mi * 16 + kb * 4 + rot) & 31;
            *reinterpret_cast<float4*>(&Ut[col * 36 + slot]) =
                make_float4(Uv[mi * 4], Uv[mi * 4 + 1], Uv[mi * 4 + 2], Uv[mi * 4 + 3]);
        }
    }
    Vs[tid] = vkeep;   // Vs[w*64+kb*16+r16] = V_{head w*4+kb}[r16]/sqrt(8)

    wave_ds_fence();   // all readers below touch only this wave's cols

    // ---- phase 2: thread = o = tid ----
    const int rot2 = 8 * (n & 3);

    float4 u4[8];                      // U[4k..4k+3][o]
    #pragma unroll
    for (int k = 0; k < 8; ++k)
        u4[k] = *reinterpret_cast<const float4*>(&Ut[tid * 36 + ((4 * k + rot2) & 31)]);

    // scores s[q] = sum_d V[d]*U[q][d], q = j and j+16
    const int slot0 = (j + rot2) & 31;
    const int slot1 = slot0 ^ 16;
    float s0 = 0.f, s1 = 0.f;
    #pragma unroll
    for (int kk = 0; kk < 4; ++kk) {
        const float4 vq = *reinterpret_cast<const float4*>(&Vs[n * 16 + 4 * kk]);
        const float* up = &Ut[(n * 16 + 4 * kk) * 36];
        s0 = fmaf(up[0 * 36 + slot0], vq.x, s0);  s1 = fmaf(up[0 * 36 + slot1], vq.x, s1);
        s0 = fmaf(up[1 * 36 + slot0], vq.y, s0);  s1 = fmaf(up[1 * 36 + slot1], vq.y, s1);
        s0 = fmaf(up[2 * 36 + slot0], vq.z, s0);  s1 = fmaf(up[2 * 36 + slot1], vq.z, s1);
        s0 = fmaf(up[3 * 36 + slot0], vq.w, s0);  s1 = fmaf(up[3 * 36 + slot1], vq.w, s1);
    }

    // softmax over 32 q (16-lane-group shuffles)
    float m = fmaxf(s0, s1);
    #pragma unroll
    for (int mask = 1; mask <= 8; mask <<= 1) m = fmaxf(m, __shfl_xor(m, mask));
    const float e0 = __expf(s0 - m), e1 = __expf(s1 - m);
    float es = e0 + e1;
    #pragma unroll
    for (int mask = 1; mask <= 8; mask <<= 1) es += __shfl_xor(es, mask);
    const float inv = __builtin_amdgcn_rcpf(es);

    cs[n * 36 + slot0] = fmaf(e0, inv, bwj0);
    cs[n * 36 + slot1] = fmaf(e1, inv, bwj1);

    wave_ds_fence();   // cs written/read within the same 16-lane head group

    // out[o] = sum_q c[q] * U[q][o]
    float od = 0.f;
    #pragma unroll
    for (int k = 0; k < 8; ++k) {
        const float4 cq = *reinterpret_cast<const float4*>(&cs[n * 36 + ((4 * k + rot2) & 31)]);
        od = fmaf(cq.x, u4[k].x, od);
        od = fmaf(cq.y, u4[k].y, od);
        od = fmaf(cq.z, u4[k].z, od);
        od = fmaf(cq.w, u4[k].w, od);
    }

    // norm gate over d (16-lane group)
    float ss = od * od;
    #pragma unroll
    for (int mask = 1; mask <= 8; mask <<= 1) ss += __shfl_xor(ss, mask);
    const float nrm = sqrtf(ss);
    const float res = ss * __builtin_amdgcn_rcpf(ss + 1.f) *
                      (od * __builtin_amdgcn_rcpf(nrm + 1e-7f));

    out[(size_t)bt * 256 + tid] = res;
}

extern "C" void kernel_launch(void* const* d_in, const int* in_sizes, int n_in,
                              void* d_out, int out_size, void* d_ws, size_t ws_size,
                              hipStream_t stream) {
    const float* x    = (const float*)d_in[0];
    const float* K    = (const float*)d_in[1];
    const float* bias = (const float*)d_in[2];
    const float* Bw   = (const float*)d_in[3];
    float* out        = (float*)d_out;
    uint4* Kp         = (uint4*)d_ws;            // 16 KB scratch

    kpack_kernel<<<1, 256, 0, stream>>>(K, Kp);

    const int B  = in_sizes[0] / (T_DIM * 32 * 8);   // = 8
    const int nb = B * T_DIM;                        // 8192 blocks
    caps_kernel<<<nb, 256, 0, stream>>>(x, bias, Bw, Kp, out);
}